// Round 1
// baseline (869.352 us; speedup 1.0000x reference)
//
#include <hip/hip_runtime.h>

constexpr int D_IN  = 128;
constexpr int NEIGH = 25;
constexpr int D_HID = 32;
constexpr int D_OUT = 32;
constexpr float ALPHA = 0.02f;

__device__ __forceinline__ float leaky(float x) { return fmaxf(x, ALPHA * x); }

// 2 threads per row: thread "hf" in {0,1} handles neighbors [13*hf, 13+12*hf)
// and half of the final projections; pair combines via __shfl_xor(.,1).
__global__ __launch_bounds__(256, 2)
void sage_maxpool(const float* __restrict__ self_vecs,
                  const float* __restrict__ neigh_vecs,
                  const float* __restrict__ W_mlp,
                  const float* __restrict__ b_mlp,
                  const float* __restrict__ W_va,
                  const float* __restrict__ W_neigh,
                  float* __restrict__ out,
                  int N)
{
    __shared__ float sWmlp[D_IN * D_HID];   // 16 KB, [d][h]
    __shared__ float sWva [D_IN * D_OUT];   // 16 KB, [d][o]
    __shared__ float sWn  [D_HID * D_OUT];  //  4 KB, [h][o]
    __shared__ float sb   [D_HID];

    {
        float4*       dst1 = reinterpret_cast<float4*>(sWmlp);
        const float4* src1 = reinterpret_cast<const float4*>(W_mlp);
        float4*       dst2 = reinterpret_cast<float4*>(sWva);
        const float4* src2 = reinterpret_cast<const float4*>(W_va);
        for (int i = threadIdx.x; i < D_IN * D_HID / 4; i += blockDim.x) {
            dst1[i] = src1[i];
            dst2[i] = src2[i];
        }
        float4*       dst3 = reinterpret_cast<float4*>(sWn);
        const float4* src3 = reinterpret_cast<const float4*>(W_neigh);
        for (int i = threadIdx.x; i < D_HID * D_OUT / 4; i += blockDim.x)
            dst3[i] = src3[i];
        if (threadIdx.x < D_HID) sb[threadIdx.x] = b_mlp[threadIdx.x];
    }
    __syncthreads();

    const int gtid = blockIdx.x * blockDim.x + threadIdx.x;
    const int row  = gtid >> 1;
    const int hf   = gtid & 1;
    if (row >= N) return;

    const float4* xrow = reinterpret_cast<const float4*>(neigh_vecs)
                       + (size_t)row * (NEIGH * D_IN / 4);

    float nh[D_HID];
#pragma unroll
    for (int h = 0; h < D_HID; ++h) nh[h] = -3.0e38f;

    const int n0 = hf ? 13 : 0;
    const int n1 = hf ? NEIGH : 13;

    for (int n = n0; n < n1; ++n) {
        float acc[D_HID];
#pragma unroll
        for (int h4 = 0; h4 < D_HID / 4; ++h4) {
            float4 b4 = reinterpret_cast<const float4*>(sb)[h4];
            acc[h4*4+0] = b4.x; acc[h4*4+1] = b4.y;
            acc[h4*4+2] = b4.z; acc[h4*4+3] = b4.w;
        }
        const float4* x4 = xrow + n * (D_IN / 4);
#pragma unroll 2
        for (int d4 = 0; d4 < D_IN / 4; ++d4) {
            float4 xv = x4[d4];
            float xs[4] = {xv.x, xv.y, xv.z, xv.w};
#pragma unroll
            for (int k = 0; k < 4; ++k) {
                const float4* wrow =
                    reinterpret_cast<const float4*>(&sWmlp[(d4*4 + k) * D_HID]);
                const float xk = xs[k];
#pragma unroll
                for (int h4 = 0; h4 < D_HID / 4; ++h4) {
                    float4 w = wrow[h4];
                    acc[h4*4+0] = fmaf(xk, w.x, acc[h4*4+0]);
                    acc[h4*4+1] = fmaf(xk, w.y, acc[h4*4+1]);
                    acc[h4*4+2] = fmaf(xk, w.z, acc[h4*4+2]);
                    acc[h4*4+3] = fmaf(xk, w.w, acc[h4*4+3]);
                }
            }
        }
#pragma unroll
        for (int h = 0; h < D_HID; ++h) nh[h] = fmaxf(nh[h], leaky(acc[h]));
    }

    // combine the pair's max (pair = lanes 2i, 2i+1 in the same wave)
#pragma unroll
    for (int h = 0; h < D_HID; ++h) nh[h] = fmaxf(nh[h], __shfl_xor(nh[h], 1));

    // ---- final projections: split d-range (and W_neigh h-range) across pair ----
    float acc2[D_OUT];
#pragma unroll
    for (int o = 0; o < D_OUT; ++o) acc2[o] = 0.0f;

    const float4* srow = reinterpret_cast<const float4*>(self_vecs)
                       + (size_t)row * (D_IN / 4);
    const int dbase = hf * (D_IN / 8);   // 16 float4 each
#pragma unroll
    for (int i = 0; i < D_IN / 8; ++i) {
        float4 sv = srow[dbase + i];
        float ss[4] = {sv.x, sv.y, sv.z, sv.w};
        const int d0 = (dbase + i) * 4;
#pragma unroll
        for (int k = 0; k < 4; ++k) {
            const float4* wrow =
                reinterpret_cast<const float4*>(&sWva[(d0 + k) * D_OUT]);
            const float sk = ss[k];
#pragma unroll
            for (int o4 = 0; o4 < D_OUT / 4; ++o4) {
                float4 w = wrow[o4];
                acc2[o4*4+0] = fmaf(sk, w.x, acc2[o4*4+0]);
                acc2[o4*4+1] = fmaf(sk, w.y, acc2[o4*4+1]);
                acc2[o4*4+2] = fmaf(sk, w.z, acc2[o4*4+2]);
                acc2[o4*4+3] = fmaf(sk, w.w, acc2[o4*4+3]);
            }
        }
    }

    // W_neigh: each half handles 16 h values; nh reg index kept compile-time
#pragma unroll
    for (int i = 0; i < D_HID / 2; ++i) {
        const float nhv = hf ? nh[D_HID/2 + i] : nh[i];
        const int h = hf * (D_HID / 2) + i;            // runtime: LDS addr only
        const float4* wrow = reinterpret_cast<const float4*>(&sWn[h * D_OUT]);
#pragma unroll
        for (int o4 = 0; o4 < D_OUT / 4; ++o4) {
            float4 w = wrow[o4];
            acc2[o4*4+0] = fmaf(nhv, w.x, acc2[o4*4+0]);
            acc2[o4*4+1] = fmaf(nhv, w.y, acc2[o4*4+1]);
            acc2[o4*4+2] = fmaf(nhv, w.z, acc2[o4*4+2]);
            acc2[o4*4+3] = fmaf(nhv, w.w, acc2[o4*4+3]);
        }
    }

    // sum the pair's partial projections
#pragma unroll
    for (int o = 0; o < D_OUT; ++o) acc2[o] += __shfl_xor(acc2[o], 1);

    // each half stores 64B (compile-time reg indices via select)
    float4* orow = reinterpret_cast<float4*>(out) + (size_t)row * (D_OUT / 4);
#pragma unroll
    for (int j = 0; j < 4; ++j) {
        float4 r;
        r.x = leaky(hf ? acc2[16 + 4*j + 0] : acc2[4*j + 0]);
        r.y = leaky(hf ? acc2[16 + 4*j + 1] : acc2[4*j + 1]);
        r.z = leaky(hf ? acc2[16 + 4*j + 2] : acc2[4*j + 2]);
        r.w = leaky(hf ? acc2[16 + 4*j + 3] : acc2[4*j + 3]);
        orow[hf * 4 + j] = r;
    }
}

extern "C" void kernel_launch(void* const* d_in, const int* in_sizes, int n_in,
                              void* d_out, int out_size, void* d_ws, size_t ws_size,
                              hipStream_t stream)
{
    const float* self_vecs = (const float*)d_in[0];
    const float* neigh     = (const float*)d_in[1];
    const float* W_mlp     = (const float*)d_in[2];
    const float* b_mlp     = (const float*)d_in[3];
    const float* W_va      = (const float*)d_in[4];
    const float* W_neigh   = (const float*)d_in[5];
    float* outp            = (float*)d_out;

    const int N = in_sizes[0] / D_IN;

    const int threads = 256;
    const int total   = 2 * N;                 // 2 threads per row
    const int blocks  = (total + threads - 1) / threads;

    sage_maxpool<<<dim3(blocks), dim3(threads), 0, stream>>>(
        self_vecs, neigh, W_mlp, b_mlp, W_va, W_neigh, outp, N);
}

// Round 2
// 320.713 us; speedup vs baseline: 2.7107x; 2.7107x over previous
//
#include <hip/hip_runtime.h>
#include <stdint.h>

typedef short bf16x8 __attribute__((ext_vector_type(8)));
typedef float f32x4  __attribute__((ext_vector_type(4)));

static constexpr float ALPHA = 0.02f;

__device__ __forceinline__ float leaky(float x) { return fmaxf(x, ALPHA * x); }

// Involutive swizzle for [n][512B] row layouts staged in LDS.
// Only touches bits 4..8 as a function of bits 9..12 -> involution, keeps
// 16B alignment, spreads the 512B row stride across all 32 banks.
__device__ __forceinline__ unsigned swz(unsigned b) {
    unsigned n = (b >> 9) & 15u;
    return b ^ (n << 5) ^ (((n >> 2) & 1u) << 4);
}

__device__ __forceinline__ short f2bf(float f) {  // RNE f32 -> bf16
    unsigned u = __builtin_bit_cast(unsigned, f);
    unsigned r = (u + 0x7FFFu + ((u >> 16) & 1u)) >> 16;
    return (short)r;
}

__device__ __forceinline__ void gload16(const void* g, void* l) {
    __builtin_amdgcn_global_load_lds(
        (const __attribute__((address_space(1))) unsigned*)g,
        (__attribute__((address_space(3))) unsigned*)l, 16, 0, 0);
}

// Read 8 logically-consecutive f32 (one MFMA A-frag) from swizzled LDS, cvt to bf16.
__device__ __forceinline__ bf16x8 frag_from_lds(const char* base, unsigned L) {
    const float4 a = *(const float4*)(base + swz(L));
    const float4 b = *(const float4*)(base + swz(L + 16u));
    bf16x8 r;
    r[0] = f2bf(a.x); r[1] = f2bf(a.y); r[2] = f2bf(a.z); r[3] = f2bf(a.w);
    r[4] = f2bf(b.x); r[5] = f2bf(b.y); r[6] = f2bf(b.z); r[7] = f2bf(b.w);
    return r;
}

// One wave (64 threads) per block; each wave owns 16 rows.
// GEMM1: [(row,neigh) x 128] * W_mlp[128x32] via mfma_f32_16x16x32_bf16,
//        neighbors padded 25->32 (2 M-tiles/row), pad masked before max.
// GEMM2: [16 rows x 160] * [W_va;W_neigh] via 5 k-tiles of MFMA.
__global__ __launch_bounds__(64, 1)
void sage_mfma(const float* __restrict__ self_vecs,
               const float* __restrict__ xg,
               const float* __restrict__ W_mlp,
               const float* __restrict__ b_mlp,
               const float* __restrict__ W_va,
               const float* __restrict__ W_neigh,
               float* __restrict__ out, int N)
{
    __shared__ __align__(16) char  buf0[13312];
    __shared__ __align__(16) char  buf1[13312];
    __shared__ __align__(16) float nhbuf[16 * 36];   // [row][h], stride 36 to spread banks

    const int lane = threadIdx.x & 63;
    const int n15  = lane & 15;
    const int g    = lane >> 4;
    const unsigned wid  = blockIdx.x;
    const unsigned row0 = wid * 16u;

    const unsigned xlimit = (unsigned)N * 12800u - 16u;  // clamp for row N-1 tail over-read

    // ---- prologue: stage row 0 (13 KB, 13 x global_load_lds_dwordx4) ----
    {
        unsigned base = row0 * 12800u;
#pragma unroll
        for (int i = 0; i < 13; ++i) {
            unsigned dl  = (unsigned)(i * 1024 + lane * 16);
            unsigned src = base + swz(dl);
            src = src > xlimit ? xlimit : src;
            gload16((const char*)xg + src, buf0 + i * 1024);
        }
    }

    // ---- load B fragments (weights) into registers, once per wave ----
    // k-map (kt*32 + g*8 + j) is applied identically to A and B -> any HW
    // k-permutation cancels. N-map: col = lane&15 (m89-verified D layout).
    bf16x8 B1[2][4], B2[2][5];
#pragma unroll
    for (int ht = 0; ht < 2; ++ht) {
#pragma unroll
        for (int kt = 0; kt < 4; ++kt) {
            bf16x8 r1, r2;
#pragma unroll
            for (int j = 0; j < 8; ++j) {
                int k = kt * 32 + g * 8 + j;
                r1[j] = f2bf(W_mlp[k * 32 + ht * 16 + n15]);
                r2[j] = f2bf(W_va [k * 32 + ht * 16 + n15]);
            }
            B1[ht][kt] = r1; B2[ht][kt] = r2;
        }
        bf16x8 r3;
#pragma unroll
        for (int j = 0; j < 8; ++j)
            r3[j] = f2bf(W_neigh[(g * 8 + j) * 32 + ht * 16 + n15]);
        B2[ht][4] = r3;
    }
    const float bl = b_mlp[n15], bh = b_mlp[16 + n15];

    const f32x4 zero4 = {0.f, 0.f, 0.f, 0.f};

    // ---- main loop: double-buffered rows, counted vmcnt (never 0 mid-loop) ----
#pragma unroll 2
    for (int r = 0; r < 16; ++r) {
        char* cur = (r & 1) ? buf1 : buf0;
        char* nxt = (r & 1) ? buf0 : buf1;

        if (r < 15) {
            unsigned base = (row0 + (unsigned)r + 1u) * 12800u;
#pragma unroll
            for (int i = 0; i < 13; ++i) {
                unsigned dl  = (unsigned)(i * 1024 + lane * 16);
                unsigned src = base + swz(dl);
                src = src > xlimit ? xlimit : src;
                gload16((const char*)xg + src, nxt + i * 1024);
            }
            asm volatile("s_waitcnt vmcnt(13)" ::: "memory");  // cur's 13 done, next 13 in flight
        } else {
            // overlap: stage the 16 self rows (8 KB) into buf0 for GEMM2
            unsigned base = row0 * 512u;
#pragma unroll
            for (int i = 0; i < 8; ++i) {
                unsigned dl = (unsigned)(i * 1024 + lane * 16);
                gload16((const char*)self_vecs + base + swz(dl), buf0 + i * 1024);
            }
            asm volatile("s_waitcnt vmcnt(8)" ::: "memory");   // cur done, self in flight
        }
        __builtin_amdgcn_sched_barrier(0);

        f32x4 acc[2][2];  // [Mtile][htile]
        acc[0][0] = zero4; acc[0][1] = zero4; acc[1][0] = zero4; acc[1][1] = zero4;

        const unsigned nA = (unsigned)n15;                       // neigh 0..15
        const unsigned nB = (unsigned)((n15 < 9) ? (16 + n15) : 8);  // neigh 16..24, pad clamped

#pragma unroll
        for (int kt = 0; kt < 4; ++kt) {
            bf16x8 a = frag_from_lds(cur, nA * 512u + (unsigned)(kt * 128 + g * 32));
            acc[0][0] = __builtin_amdgcn_mfma_f32_16x16x32_bf16(a, B1[0][kt], acc[0][0], 0, 0, 0);
            acc[0][1] = __builtin_amdgcn_mfma_f32_16x16x32_bf16(a, B1[1][kt], acc[0][1], 0, 0, 0);
        }
#pragma unroll
        for (int kt = 0; kt < 4; ++kt) {
            bf16x8 a = frag_from_lds(cur, nB * 512u + (unsigned)(kt * 128 + g * 32));
            acc[1][0] = __builtin_amdgcn_mfma_f32_16x16x32_bf16(a, B1[0][kt], acc[1][0], 0, 0, 0);
            acc[1][1] = __builtin_amdgcn_mfma_f32_16x16x32_bf16(a, B1[1][kt], acc[1][1], 0, 0, 0);
        }

        // max over neighbors (leaky monotonic: raw max -> +b -> leaky)
#pragma unroll
        for (int ht = 0; ht < 2; ++ht) {
            float m = -3.0e38f;
#pragma unroll
            for (int q = 0; q < 4; ++q) m = fmaxf(m, acc[0][ht][q]);
#pragma unroll
            for (int q = 0; q < 4; ++q) {
                float v = (g * 4 + q < 9) ? acc[1][ht][q] : -3.0e38f;  // mask pad neigh >= 25
                m = fmaxf(m, v);
            }
            m = fmaxf(m, __shfl_xor(m, 16));
            m = fmaxf(m, __shfl_xor(m, 32));
            float nhv = leaky(m + (ht ? bh : bl));
            if (lane < 16) nhbuf[r * 36 + ht * 16 + n15] = nhv;
        }
    }

    // ---- GEMM2: out = leaky(self @ W_va + nh @ W_neigh) ----
    asm volatile("s_waitcnt vmcnt(0)" ::: "memory");  // self staging done
    __builtin_amdgcn_sched_barrier(0);

    f32x4 acc2[2];
    acc2[0] = zero4; acc2[1] = zero4;

#pragma unroll
    for (int kt = 0; kt < 4; ++kt) {
        bf16x8 a = frag_from_lds(buf0, (unsigned)n15 * 512u + (unsigned)(kt * 128 + g * 32));
        acc2[0] = __builtin_amdgcn_mfma_f32_16x16x32_bf16(a, B2[0][kt], acc2[0], 0, 0, 0);
        acc2[1] = __builtin_amdgcn_mfma_f32_16x16x32_bf16(a, B2[1][kt], acc2[1], 0, 0, 0);
    }
    {
        const float4 p = *(const float4*)&nhbuf[n15 * 36 + g * 8];
        const float4 q = *(const float4*)&nhbuf[n15 * 36 + g * 8 + 4];
        bf16x8 a;
        a[0] = f2bf(p.x); a[1] = f2bf(p.y); a[2] = f2bf(p.z); a[3] = f2bf(p.w);
        a[4] = f2bf(q.x); a[5] = f2bf(q.y); a[6] = f2bf(q.z); a[7] = f2bf(q.w);
        acc2[0] = __builtin_amdgcn_mfma_f32_16x16x32_bf16(a, B2[0][4], acc2[0], 0, 0, 0);
        acc2[1] = __builtin_amdgcn_mfma_f32_16x16x32_bf16(a, B2[1][4], acc2[1], 0, 0, 0);
    }

    // D layout: row = g*4 + reg, col = ht*16 + n15
#pragma unroll
    for (int ht = 0; ht < 2; ++ht) {
#pragma unroll
        for (int q = 0; q < 4; ++q) {
            unsigned row = row0 + (unsigned)(g * 4 + q);
            out[(size_t)row * 32u + (unsigned)(ht * 16 + n15)] = leaky(acc2[ht][q]);
        }
    }
}

extern "C" void kernel_launch(void* const* d_in, const int* in_sizes, int n_in,
                              void* d_out, int out_size, void* d_ws, size_t ws_size,
                              hipStream_t stream)
{
    const float* self_vecs = (const float*)d_in[0];
    const float* neigh     = (const float*)d_in[1];
    const float* W_mlp     = (const float*)d_in[2];
    const float* b_mlp     = (const float*)d_in[3];
    const float* W_va      = (const float*)d_in[4];
    const float* W_neigh   = (const float*)d_in[5];
    float* outp            = (float*)d_out;

    const int N = in_sizes[0] / 128;   // 131072, divisible by 16

    sage_mfma<<<dim3(N / 16), dim3(64), 0, stream>>>(
        self_vecs, neigh, W_mlp, b_mlp, W_va, W_neigh, outp, N);
}

// Round 3
// 314.614 us; speedup vs baseline: 2.7632x; 1.0194x over previous
//
#include <hip/hip_runtime.h>
#include <stdint.h>

typedef short bf16x8 __attribute__((ext_vector_type(8)));
typedef float f32x4  __attribute__((ext_vector_type(4)));

static constexpr float ALPHA = 0.02f;

__device__ __forceinline__ float leaky(float x) { return fmaxf(x, ALPHA * x); }

// Involutive swizzle for [n][512B] row layouts staged in LDS.
// Touches bits 4..8 as a function of bits 9..12 -> involution, keeps
// 16B alignment, spreads the 512B row stride across all 32 banks.
__device__ __forceinline__ unsigned swz(unsigned b) {
    unsigned n = (b >> 9) & 15u;
    return b ^ (n << 5) ^ (((n >> 2) & 1u) << 4);
}

__device__ __forceinline__ short f2bf(float f) {  // RNE f32 -> bf16
    unsigned u = __builtin_bit_cast(unsigned, f);
    unsigned r = (u + 0x7FFFu + ((u >> 16) & 1u)) >> 16;
    return (short)r;
}

__device__ __forceinline__ void gload16(const void* g, void* l) {
    __builtin_amdgcn_global_load_lds(
        (const __attribute__((address_space(1))) unsigned*)g,
        (__attribute__((address_space(3))) unsigned*)l, 16, 0, 0);
}

// Read 8 logically-consecutive f32 (one MFMA A-frag) from swizzled LDS, cvt to bf16.
__device__ __forceinline__ bf16x8 frag_from_lds(const char* base, unsigned L) {
    const float4 a = *(const float4*)(base + swz(L));
    const float4 b = *(const float4*)(base + swz(L + 16u));
    bf16x8 r;
    r[0] = f2bf(a.x); r[1] = f2bf(a.y); r[2] = f2bf(a.z); r[3] = f2bf(a.w);
    r[4] = f2bf(b.x); r[5] = f2bf(b.y); r[6] = f2bf(b.z); r[7] = f2bf(b.w);
    return r;
}

// One wave per block, 16 rows per wave. Row split into two fixed-buffer
// chunks: A = neigh 0..15 (8KB, bufA), B = neigh 16..24 +1 pad (5KB, bufB).
// LDS = 15.6KB/block -> 10 waves/CU. Counted vmcnt pipeline: while computing
// chunk i, chunk i+1 is in flight (alternating vmcnt(5)/vmcnt(8), never 0
// mid-loop). Self rows stage into bufA overlapped with the last B-chunk.
__global__ __launch_bounds__(64, 2)
void sage_mfma(const float* __restrict__ self_vecs,
               const float* __restrict__ xg,
               const float* __restrict__ W_mlp,
               const float* __restrict__ b_mlp,
               const float* __restrict__ W_va,
               const float* __restrict__ W_neigh,
               float* __restrict__ out, int N)
{
    __shared__ __align__(16) char  bufA[8192];       // 16 neighbors / self rows
    __shared__ __align__(16) char  bufB[5120];       // 10 neighbors (9 real + 1 pad)
    __shared__ __align__(16) float nhbuf[16 * 36];   // [row][h], stride 36

    const int lane = threadIdx.x & 63;
    const int n15  = lane & 15;
    const int g    = lane >> 4;
    const unsigned row0 = blockIdx.x * 16u;

    const unsigned xlimit = (unsigned)N * 12800u - 16u;  // last-row tail clamp (B only)

    // ---- prologue: stage chunk A of row 0 (8 x global_load_lds_dwordx4) ----
    {
        unsigned base = row0 * 12800u;
#pragma unroll
        for (int i = 0; i < 8; ++i) {
            unsigned dl = (unsigned)(i * 1024) + (unsigned)lane * 16u;
            gload16((const char*)xg + base + swz(dl), bufA + i * 1024);
        }
    }

    // ---- B fragments (weights) in registers, once per wave ----
    // k-map (kt*32 + g*8 + j) identical on A and B -> HW k-permutation cancels.
    bf16x8 B1[2][4], B2[2][5];
#pragma unroll
    for (int ht = 0; ht < 2; ++ht) {
#pragma unroll
        for (int kt = 0; kt < 4; ++kt) {
            bf16x8 r1, r2;
#pragma unroll
            for (int j = 0; j < 8; ++j) {
                int k = kt * 32 + g * 8 + j;
                r1[j] = f2bf(W_mlp[k * 32 + ht * 16 + n15]);
                r2[j] = f2bf(W_va [k * 32 + ht * 16 + n15]);
            }
            B1[ht][kt] = r1; B2[ht][kt] = r2;
        }
        bf16x8 r3;
#pragma unroll
        for (int j = 0; j < 8; ++j)
            r3[j] = f2bf(W_neigh[(g * 8 + j) * 32 + ht * 16 + n15]);
        B2[ht][4] = r3;
    }
    const float bl = b_mlp[n15], bh = b_mlp[16 + n15];

    const f32x4 zero4 = {0.f, 0.f, 0.f, 0.f};

#pragma unroll 1
    for (int r = 0; r < 16; ++r) {
        const unsigned rowbase = (row0 + (unsigned)r) * 12800u;

        // issue chunk B of row r (neigh 16..25; #25 is pad, clamped at EOD)
        __builtin_amdgcn_sched_barrier(0);
#pragma unroll
        for (int i = 0; i < 5; ++i) {
            unsigned dl  = (unsigned)(i * 1024) + (unsigned)lane * 16u;
            unsigned src = rowbase + 8192u + swz(dl);
            src = src > xlimit ? xlimit : src;
            gload16((const char*)xg + src, bufB + i * 1024);
        }
        asm volatile("s_waitcnt vmcnt(5)" ::: "memory");  // A_r ready, B_r in flight
        __builtin_amdgcn_sched_barrier(0);

        // ---- compute chunk A (neigh 0..15) ----
        f32x4 accA0 = zero4, accA1 = zero4;
#pragma unroll
        for (int kt = 0; kt < 4; ++kt) {
            bf16x8 a = frag_from_lds(bufA, (unsigned)n15 * 512u + (unsigned)(kt * 128 + g * 32));
            accA0 = __builtin_amdgcn_mfma_f32_16x16x32_bf16(a, B1[0][kt], accA0, 0, 0, 0);
            accA1 = __builtin_amdgcn_mfma_f32_16x16x32_bf16(a, B1[1][kt], accA1, 0, 0, 0);
        }
        float m0 = fmaxf(fmaxf(accA0[0], accA0[1]), fmaxf(accA0[2], accA0[3]));
        float m1 = fmaxf(fmaxf(accA1[0], accA1[1]), fmaxf(accA1[2], accA1[3]));

        // issue chunk A of row r+1 (or the 16 self rows for GEMM2) into bufA
        __builtin_amdgcn_sched_barrier(0);
        if (r < 15) {
            unsigned nbase = (row0 + (unsigned)r + 1u) * 12800u;
#pragma unroll
            for (int i = 0; i < 8; ++i) {
                unsigned dl = (unsigned)(i * 1024) + (unsigned)lane * 16u;
                gload16((const char*)xg + nbase + swz(dl), bufA + i * 1024);
            }
        } else {
            unsigned sbase = row0 * 512u;
#pragma unroll
            for (int i = 0; i < 8; ++i) {
                unsigned dl = (unsigned)(i * 1024) + (unsigned)lane * 16u;
                gload16((const char*)self_vecs + sbase + swz(dl), bufA + i * 1024);
            }
        }
        asm volatile("s_waitcnt vmcnt(8)" ::: "memory");  // B_r ready, next A in flight
        __builtin_amdgcn_sched_barrier(0);

        // ---- compute chunk B (neigh 16..24, rows >= 9 masked) ----
        f32x4 accB0 = zero4, accB1 = zero4;
        const unsigned rb = (n15 < 10) ? (unsigned)n15 : 9u;  // clamp read row
#pragma unroll
        for (int kt = 0; kt < 4; ++kt) {
            bf16x8 a = frag_from_lds(bufB, rb * 512u + (unsigned)(kt * 128 + g * 32));
            accB0 = __builtin_amdgcn_mfma_f32_16x16x32_bf16(a, B1[0][kt], accB0, 0, 0, 0);
            accB1 = __builtin_amdgcn_mfma_f32_16x16x32_bf16(a, B1[1][kt], accB1, 0, 0, 0);
        }
#pragma unroll
        for (int q = 0; q < 4; ++q) {
            const bool real = (g * 4 + q) < 9;   // D row = neigh-16 index
            m0 = fmaxf(m0, real ? accB0[q] : -3.0e38f);
            m1 = fmaxf(m1, real ? accB1[q] : -3.0e38f);
        }
        m0 = fmaxf(m0, __shfl_xor(m0, 16));  m0 = fmaxf(m0, __shfl_xor(m0, 32));
        m1 = fmaxf(m1, __shfl_xor(m1, 16));  m1 = fmaxf(m1, __shfl_xor(m1, 32));
        if (lane < 16) {
            nhbuf[r * 36 + n15]      = leaky(m0 + bl);
            nhbuf[r * 36 + 16 + n15] = leaky(m1 + bh);
        }
    }

    // ---- GEMM2: out = leaky(self @ W_va + nh @ W_neigh), self in bufA ----
    asm volatile("s_waitcnt vmcnt(0)" ::: "memory");
    __builtin_amdgcn_sched_barrier(0);

    f32x4 acc2[2];
    acc2[0] = zero4; acc2[1] = zero4;

#pragma unroll
    for (int kt = 0; kt < 4; ++kt) {
        bf16x8 a = frag_from_lds(bufA, (unsigned)n15 * 512u + (unsigned)(kt * 128 + g * 32));
        acc2[0] = __builtin_amdgcn_mfma_f32_16x16x32_bf16(a, B2[0][kt], acc2[0], 0, 0, 0);
        acc2[1] = __builtin_amdgcn_mfma_f32_16x16x32_bf16(a, B2[1][kt], acc2[1], 0, 0, 0);
    }
    {
        const float4 p = *(const float4*)&nhbuf[n15 * 36 + g * 8];
        const float4 q = *(const float4*)&nhbuf[n15 * 36 + g * 8 + 4];
        bf16x8 a;
        a[0] = f2bf(p.x); a[1] = f2bf(p.y); a[2] = f2bf(p.z); a[3] = f2bf(p.w);
        a[4] = f2bf(q.x); a[5] = f2bf(q.y); a[6] = f2bf(q.z); a[7] = f2bf(q.w);
        acc2[0] = __builtin_amdgcn_mfma_f32_16x16x32_bf16(a, B2[0][4], acc2[0], 0, 0, 0);
        acc2[1] = __builtin_amdgcn_mfma_f32_16x16x32_bf16(a, B2[1][4], acc2[1], 0, 0, 0);
    }

    // D layout: row = g*4 + reg, col = ht*16 + n15
#pragma unroll
    for (int ht = 0; ht < 2; ++ht) {
#pragma unroll
        for (int q = 0; q < 4; ++q) {
            unsigned row = row0 + (unsigned)(g * 4 + q);
            out[(size_t)row * 32u + (unsigned)(ht * 16 + n15)] = leaky(acc2[ht][q]);
        }
    }
}

extern "C" void kernel_launch(void* const* d_in, const int* in_sizes, int n_in,
                              void* d_out, int out_size, void* d_ws, size_t ws_size,
                              hipStream_t stream)
{
    const float* self_vecs = (const float*)d_in[0];
    const float* neigh     = (const float*)d_in[1];
    const float* W_mlp     = (const float*)d_in[2];
    const float* b_mlp     = (const float*)d_in[3];
    const float* W_va      = (const float*)d_in[4];
    const float* W_neigh   = (const float*)d_in[5];
    float* outp            = (float*)d_out;

    const int N = in_sizes[0] / 128;   // 131072, divisible by 16

    sage_mfma<<<dim3(N / 16), dim3(64), 0, stream>>>(
        self_vecs, neigh, W_mlp, b_mlp, W_va, W_neigh, outp, N);
}

// Round 4
// 311.799 us; speedup vs baseline: 2.7882x; 1.0090x over previous
//
#include <hip/hip_runtime.h>
#include <hip/hip_bf16.h>
#include <stdint.h>

typedef short bf16x8 __attribute__((ext_vector_type(8)));
typedef float f32x4  __attribute__((ext_vector_type(4)));

static constexpr float ALPHA = 0.02f;

__device__ __forceinline__ float leaky(float x) { return fmaxf(x, ALPHA * x); }

// Involutive swizzle for [n][512B] row layouts staged in LDS.
// Touches bits 4..8 as a function of bits 9..12 -> involution, keeps
// 16B alignment, spreads the 512B row stride across all 32 banks.
__device__ __forceinline__ unsigned swz(unsigned b) {
    unsigned n = (b >> 9) & 15u;
    return b ^ (n << 5) ^ (((n >> 2) & 1u) << 4);
}

__device__ __forceinline__ short f2bf(float f) {  // HW RNE cvt (compiler pairs to v_cvt_pk_bf16_f32)
    return __builtin_bit_cast(short, __float2bfloat16(f));
}

__device__ __forceinline__ void gload16(const void* g, void* l) {
    __builtin_amdgcn_global_load_lds(
        (const __attribute__((address_space(1))) unsigned*)g,
        (__attribute__((address_space(3))) unsigned*)l, 16, 0, 0);
}

// Read 8 logically-consecutive f32 (one MFMA A-frag) from swizzled LDS, cvt to bf16.
__device__ __forceinline__ bf16x8 frag_from_lds(const char* base, unsigned L) {
    const float4 a = *(const float4*)(base + swz(L));
    const float4 b = *(const float4*)(base + swz(L + 16u));
    bf16x8 r;
    r[0] = f2bf(a.x); r[1] = f2bf(a.y); r[2] = f2bf(a.z); r[3] = f2bf(a.w);
    r[4] = f2bf(b.x); r[5] = f2bf(b.y); r[6] = f2bf(b.z); r[7] = f2bf(b.w);
    return r;
}

// One wave per block, 16 rows per wave. Row split into two fixed-buffer
// chunks: A = neigh 0..15 (8KB, bufA), B = neigh 16..24 +1 pad (5KB, bufB).
// LDS = 15.6KB/block -> 10 waves/CU. Counted vmcnt pipeline: while computing
// chunk i, chunk i+1 is in flight (alternating vmcnt(5)/vmcnt(8), never 0
// mid-loop). Self rows stage into bufA overlapped with the last B-chunk.
// Issue order B_r then A_{r+1} makes each wave a single sequential 204.8 KB
// HBM read stream.
__global__ __launch_bounds__(64, 2)
void sage_mfma(const float* __restrict__ self_vecs,
               const float* __restrict__ xg,
               const float* __restrict__ W_mlp,
               const float* __restrict__ b_mlp,
               const float* __restrict__ W_va,
               const float* __restrict__ W_neigh,
               float* __restrict__ out, int N)
{
    __shared__ __align__(16) char  bufA[8192];       // 16 neighbors / self rows
    __shared__ __align__(16) char  bufB[5120];       // 10 neighbors (9 real + 1 pad)
    __shared__ __align__(16) float nhbuf[16 * 36];   // [row][h], stride 36

    const int lane = threadIdx.x & 63;
    const int n15  = lane & 15;
    const int g    = lane >> 4;
    const unsigned row0 = blockIdx.x * 16u;

    // Only the LAST block's pad-neighbor load can run past the buffer.
    const bool     tail   = (row0 + 16u >= (unsigned)N);
    const unsigned xlimit = (unsigned)N * 12800u - 16u;

    // ---- prologue: stage chunk A of row 0 (8 x global_load_lds_dwordx4) ----
    {
        unsigned base = row0 * 12800u;
#pragma unroll
        for (int i = 0; i < 8; ++i) {
            unsigned dl = (unsigned)(i * 1024) + (unsigned)lane * 16u;
            gload16((const char*)xg + base + swz(dl), bufA + i * 1024);
        }
    }

    // ---- B fragments (weights) in registers, once per wave ----
    // k-map (kt*32 + g*8 + j) identical on A and B -> HW k-permutation cancels.
    bf16x8 B1[2][4], B2[2][5];
#pragma unroll
    for (int ht = 0; ht < 2; ++ht) {
#pragma unroll
        for (int kt = 0; kt < 4; ++kt) {
            bf16x8 r1, r2;
#pragma unroll
            for (int j = 0; j < 8; ++j) {
                int k = kt * 32 + g * 8 + j;
                r1[j] = f2bf(W_mlp[k * 32 + ht * 16 + n15]);
                r2[j] = f2bf(W_va [k * 32 + ht * 16 + n15]);
            }
            B1[ht][kt] = r1; B2[ht][kt] = r2;
        }
        bf16x8 r3;
#pragma unroll
        for (int j = 0; j < 8; ++j)
            r3[j] = f2bf(W_neigh[(g * 8 + j) * 32 + ht * 16 + n15]);
        B2[ht][4] = r3;
    }
    const float bl = b_mlp[n15], bh = b_mlp[16 + n15];

    const f32x4 zero4 = {0.f, 0.f, 0.f, 0.f};

#pragma unroll 1
    for (int r = 0; r < 16; ++r) {
        const unsigned rowbase = (row0 + (unsigned)r) * 12800u;

        // issue chunk B of row r (neigh 16..25; #25 is pad, clamped only in tail block)
        if (tail) {
#pragma unroll
            for (int i = 0; i < 5; ++i) {
                unsigned dl  = (unsigned)(i * 1024) + (unsigned)lane * 16u;
                unsigned src = rowbase + 8192u + swz(dl);
                src = src > xlimit ? xlimit : src;
                gload16((const char*)xg + src, bufB + i * 1024);
            }
        } else {
#pragma unroll
            for (int i = 0; i < 5; ++i) {
                unsigned dl = (unsigned)(i * 1024) + (unsigned)lane * 16u;
                gload16((const char*)xg + rowbase + 8192u + swz(dl), bufB + i * 1024);
            }
        }
        asm volatile("s_waitcnt vmcnt(5)" ::: "memory");  // A_r ready, B_r in flight
        __builtin_amdgcn_sched_barrier(0);

        // ---- compute chunk A (neigh 0..15) ----
        f32x4 accA0 = zero4, accA1 = zero4;
#pragma unroll
        for (int kt = 0; kt < 4; ++kt) {
            bf16x8 a = frag_from_lds(bufA, (unsigned)n15 * 512u + (unsigned)(kt * 128 + g * 32));
            accA0 = __builtin_amdgcn_mfma_f32_16x16x32_bf16(a, B1[0][kt], accA0, 0, 0, 0);
            accA1 = __builtin_amdgcn_mfma_f32_16x16x32_bf16(a, B1[1][kt], accA1, 0, 0, 0);
        }
        float m0 = fmaxf(fmaxf(accA0[0], accA0[1]), fmaxf(accA0[2], accA0[3]));
        float m1 = fmaxf(fmaxf(accA1[0], accA1[1]), fmaxf(accA1[2], accA1[3]));

        // issue chunk A of row r+1 (or the 16 self rows for GEMM2) into bufA
        if (r < 15) {
            unsigned nbase = (row0 + (unsigned)r + 1u) * 12800u;
#pragma unroll
            for (int i = 0; i < 8; ++i) {
                unsigned dl = (unsigned)(i * 1024) + (unsigned)lane * 16u;
                gload16((const char*)xg + nbase + swz(dl), bufA + i * 1024);
            }
        } else {
            unsigned sbase = row0 * 512u;
#pragma unroll
            for (int i = 0; i < 8; ++i) {
                unsigned dl = (unsigned)(i * 1024) + (unsigned)lane * 16u;
                gload16((const char*)self_vecs + sbase + swz(dl), bufA + i * 1024);
            }
        }
        asm volatile("s_waitcnt vmcnt(8)" ::: "memory");  // B_r ready, next A in flight
        __builtin_amdgcn_sched_barrier(0);

        // ---- compute chunk B (neigh 16..24, rows >= 9 masked) ----
        f32x4 accB0 = zero4, accB1 = zero4;
        const unsigned rb = (n15 < 10) ? (unsigned)n15 : 9u;  // clamp read row
#pragma unroll
        for (int kt = 0; kt < 4; ++kt) {
            bf16x8 a = frag_from_lds(bufB, rb * 512u + (unsigned)(kt * 128 + g * 32));
            accB0 = __builtin_amdgcn_mfma_f32_16x16x32_bf16(a, B1[0][kt], accB0, 0, 0, 0);
            accB1 = __builtin_amdgcn_mfma_f32_16x16x32_bf16(a, B1[1][kt], accB1, 0, 0, 0);
        }
#pragma unroll
        for (int q = 0; q < 4; ++q) {
            const bool real = (g * 4 + q) < 9;   // D row = neigh-16 index
            m0 = fmaxf(m0, real ? accB0[q] : -3.0e38f);
            m1 = fmaxf(m1, real ? accB1[q] : -3.0e38f);
        }
        m0 = fmaxf(m0, __shfl_xor(m0, 16));  m0 = fmaxf(m0, __shfl_xor(m0, 32));
        m1 = fmaxf(m1, __shfl_xor(m1, 16));  m1 = fmaxf(m1, __shfl_xor(m1, 32));
        if (lane < 16) {
            nhbuf[r * 36 + n15]      = leaky(m0 + bl);
            nhbuf[r * 36 + 16 + n15] = leaky(m1 + bh);
        }
    }

    // ---- GEMM2: out = leaky(self @ W_va + nh @ W_neigh), self in bufA ----
    asm volatile("s_waitcnt vmcnt(0)" ::: "memory");
    __builtin_amdgcn_sched_barrier(0);

    f32x4 acc2[2];
    acc2[0] = zero4; acc2[1] = zero4;

#pragma unroll
    for (int kt = 0; kt < 4; ++kt) {
        bf16x8 a = frag_from_lds(bufA, (unsigned)n15 * 512u + (unsigned)(kt * 128 + g * 32));
        acc2[0] = __builtin_amdgcn_mfma_f32_16x16x32_bf16(a, B2[0][kt], acc2[0], 0, 0, 0);
        acc2[1] = __builtin_amdgcn_mfma_f32_16x16x32_bf16(a, B2[1][kt], acc2[1], 0, 0, 0);
    }
    {
        const float4 p = *(const float4*)&nhbuf[n15 * 36 + g * 8];
        const float4 q = *(const float4*)&nhbuf[n15 * 36 + g * 8 + 4];
        bf16x8 a;
        a[0] = f2bf(p.x); a[1] = f2bf(p.y); a[2] = f2bf(p.z); a[3] = f2bf(p.w);
        a[4] = f2bf(q.x); a[5] = f2bf(q.y); a[6] = f2bf(q.z); a[7] = f2bf(q.w);
        acc2[0] = __builtin_amdgcn_mfma_f32_16x16x32_bf16(a, B2[0][4], acc2[0], 0, 0, 0);
        acc2[1] = __builtin_amdgcn_mfma_f32_16x16x32_bf16(a, B2[1][4], acc2[1], 0, 0, 0);
    }

    // D layout: row = g*4 + reg, col = ht*16 + n15
#pragma unroll
    for (int ht = 0; ht < 2; ++ht) {
#pragma unroll
        for (int q = 0; q < 4; ++q) {
            unsigned row = row0 + (unsigned)(g * 4 + q);
            out[(size_t)row * 32u + (unsigned)(ht * 16 + n15)] = leaky(acc2[ht][q]);
        }
    }
}

extern "C" void kernel_launch(void* const* d_in, const int* in_sizes, int n_in,
                              void* d_out, int out_size, void* d_ws, size_t ws_size,
                              hipStream_t stream)
{
    const float* self_vecs = (const float*)d_in[0];
    const float* neigh     = (const float*)d_in[1];
    const float* W_mlp     = (const float*)d_in[2];
    const float* b_mlp     = (const float*)d_in[3];
    const float* W_va      = (const float*)d_in[4];
    const float* W_neigh   = (const float*)d_in[5];
    float* outp            = (float*)d_out;

    const int N = in_sizes[0] / 128;   // 131072, divisible by 16

    sage_mfma<<<dim3(N / 16), dim3(64), 0, stream>>>(
        self_vecs, neigh, W_mlp, b_mlp, W_va, W_neigh, outp, N);
}